// Round 14
// baseline (271.172 us; speedup 1.0000x reference)
//
#include <hip/hip_runtime.h>

// Problem: T=128, B=64, STATE=32, LATENT=16, AC=8, MS=8, SE=64, AE=16, H=64, OUT=18
// d_out layout: [0] = kl_loss, [1 .. 8192] = recon_loss[s*64+b]  (out_size = 8193, f32)
// d_ws layout:  [0, 6291456)  xi  (T,B,192) f32   = embed@Wi + bi
//               [6291456, 8388608) hid0 (T,B,64) f32
//               [8388608, +4) work-steal counter

#define XI_OFF   0
#define HID_OFF  6291456
#define CTR_OFF  8388608

typedef float f32x16 __attribute__((ext_vector_type(16)));
typedef _Float16 h2 __attribute__((ext_vector_type(2)));

#if __has_builtin(__builtin_amdgcn_fdot2)
#define DOT2(a, b, c) __builtin_amdgcn_fdot2((a), (b), (c), false)
#else
#define DOT2(a, b, c) ((c) + (float)(a).x * (float)(b).x + (float)(a).y * (float)(b).y)
#endif

// pack {h[lane], h[lane^1]} into h2 using DPP quad_perm [1,0,3,2] (VALU, no LDS)
__device__ __forceinline__ h2 pack_pair(float h) {
  int hb = __builtin_bit_cast(int, h);
  int hp = __builtin_amdgcn_mov_dpp(hb, 0xB1, 0xF, 0xF, true);  // lane^1
  return __builtin_bit_cast(h2, __builtin_amdgcn_cvt_pkrtz(h, __builtin_bit_cast(float, hp)));
}

// ---------------- Fused precompute (blocks 0..255) + KL (blocks 256..319) ----------------
__global__ __launch_bounds__(256, 1) void precompute_kernel(
    const float* __restrict__ state, const float* __restrict__ ac, const float* __restrict__ ms,
    const float* __restrict__ Wst, const float* __restrict__ bst,
    const float* __restrict__ Wac, const float* __restrict__ bac,
    const float* __restrict__ Wem, const float* __restrict__ bem,
    const float* __restrict__ Whd, const float* __restrict__ bhd,
    const float* __restrict__ Wi,  const float* __restrict__ bi,
    const float* __restrict__ lm, const float* __restrict__ lv,
    const float* __restrict__ lmt, const float* __restrict__ lvt,
    float* __restrict__ xi, float* __restrict__ hid0, float* __restrict__ out) {
  __shared__ float sWst[32 * 64];
  __shared__ float sWem[80 * 64];
  __shared__ float sWhd[24 * 64];
  __shared__ float sWac[8 * 16];
  __shared__ float sb[208];
  __shared__ float sin_[4][48];
  __shared__ float sse[4][80];
  __shared__ float semb[4][64];
  __shared__ float ps[4];
  int tid = threadIdx.x, lane = tid & 63, w = tid >> 6;

  if (blockIdx.x >= 256) {
    // ---- KL: 64 blocks * 256 threads * 16 iters = 262144 items ----
    float total = 0.f;
    for (int it = 0; it < 16; ++it) {
      int idx = ((int)blockIdx.x - 256) * 256 + tid + it * 16384;
      int g = idx & 31;
      int pair = idx >> 5;
      const float* M = (g < 16) ? lm : lmt;
      const float* V = (g < 16) ? lv : lvt;
      int cur = pair * 16 + (g & 15);
      float mu = M[cur], lE = V[cur];
      float m = 0.f, lS = 0.f;
      if (pair >= 64) { m = M[cur - 1024]; lS = V[cur - 1024]; }
      float d = m - mu;
      total += 0.5f * (lS - lE - 1.f + __expf(lE - lS) + d * d * __expf(-lS));
    }
    #pragma unroll
    for (int off = 32; off; off >>= 1) total += __shfl_xor(total, off);
    if (lane == 0) ps[w] = total;
    __syncthreads();
    if (tid == 0) atomicAdd(out, ps[0] + ps[1] + ps[2] + ps[3]);
    return;
  }

  // ---- precompute: 32 (t,b) pairs per block ----
  f32x16 wi0[4], wi1[4], wi2[4];
  #pragma unroll
  for (int k = 0; k < 64; ++k) {
    wi0[k >> 4][k & 15] = Wi[k * 192 + lane];
    wi1[k >> 4][k & 15] = Wi[k * 192 + 64 + lane];
    wi2[k >> 4][k & 15] = Wi[k * 192 + 128 + lane];
  }
  for (int i = tid; i < 32 * 64; i += 256) sWst[i] = Wst[i];
  for (int i = tid; i < 80 * 64; i += 256) sWem[i] = Wem[i];
  for (int i = tid; i < 24 * 64; i += 256) sWhd[i] = Whd[i];
  for (int i = tid; i < 8 * 16; i += 256) sWac[i] = Wac[i];
  if (tid < 64) sb[tid] = bst[tid];
  if (tid < 16) sb[64 + tid] = bac[tid];
  if (tid < 64) sb[80 + tid] = bem[tid];
  if (tid < 64) sb[144 + tid] = bhd[tid];
  float bi0 = bi[lane], bi1 = bi[64 + lane], bi2 = bi[128 + lane];
  __syncthreads();
  for (int cnt = 0; cnt < 8; ++cnt) {
    int pair = blockIdx.x * 32 + w * 8 + cnt;   // t*64 + b, in [0, 8192)
    if (lane < 32)      sin_[w][lane] = state[pair * 32 + lane];
    else if (lane < 40) sin_[w][lane] = ac[pair * 8 + (lane - 32)];
    else if (lane < 48) sin_[w][lane] = ms[pair * 8 + (lane - 40)];
    __syncthreads();
    float se = sb[lane];
    #pragma unroll
    for (int k = 0; k < 32; ++k) se += sin_[w][k] * sWst[k * 64 + lane];
    se = fmaxf(se, 0.f);
    float ae = 0.f;
    if (lane < 16) {
      ae = sb[64 + lane];
      #pragma unroll
      for (int k = 0; k < 8; ++k) ae += sin_[w][32 + k] * sWac[k * 16 + lane];
      ae = fmaxf(ae, 0.f);
    }
    __syncthreads();
    sse[w][lane] = se;
    if (lane < 16) sse[w][64 + lane] = ae;
    __syncthreads();
    float em = sb[80 + lane];
    #pragma unroll
    for (int k = 0; k < 80; ++k) em += sse[w][k] * sWem[k * 64 + lane];
    float hd = sb[144 + lane];
    #pragma unroll
    for (int k = 0; k < 16; ++k) hd += sse[w][64 + k] * sWhd[k * 64 + lane];
    #pragma unroll
    for (int k = 0; k < 8; ++k) hd += sin_[w][40 + k] * sWhd[(16 + k) * 64 + lane];
    hid0[pair * 64 + lane] = hd;
    semb[w][lane] = em;
    __syncthreads();
    float x0 = bi0, x1 = bi1, x2 = bi2;
    #pragma unroll
    for (int k = 0; k < 64; ++k) {
      float e = semb[w][k];
      x0 += e * wi0[k >> 4][k & 15];
      x1 += e * wi1[k >> 4][k & 15];
      x2 += e * wi2[k >> 4][k & 15];
    }
    float* xo = xi + pair * 192;
    xo[lane] = x0; xo[64 + lane] = x1; xo[128 + lane] = x2;
    __syncthreads();
  }
}

// ---------------- Rollout: TWO sequences per wave (ILP2), straight-line interleave ----
// Both slots' steps live in ONE basic block so the compiler statically interleaves
// the two independent dependence chains (in-order issue => must interleave at
// compile time). Weights (f16, 128 regs) shared between slots. Pops are uniform
// branches, ~1/18 steps. Dead slots compute harmlessly with emission masked.

#define POP(S) { \
  int _i = 0; \
  if (lane == 0) _i = (int)atomicAdd(ctr, 1u); \
  _i = __shfl(_i, 0); \
  if (_i < 8192) { \
    u##S = _i >> 6; b##S = _i & 63; s##S = 0; \
    int _pr = (u##S << 6) | b##S; \
    h##S = hid0[_pr * 64 + lane]; \
    const float* _xp = xi + _pr * 192; \
    x0##S = _xp[lane]; x1##S = _xp[64 + lane]; x2##S = _xp[128 + lane]; \
    d##S = dones[_pr]; act##S = actions[_pr]; \
    if ((lane & 1) == 0) sh2##S[lane >> 1] = pack_pair(h##S); \
    live##S = true; \
  } else live##S = false; }

#define STEP(S) { \
  int _un = (u##S < 127) ? u##S + 1 : 127; \
  int _prn = (_un << 6) | b##S; \
  const float* _xn = xi + _prn * 192; \
  float _nx0 = _xn[lane], _nx1 = _xn[64 + lane], _nx2 = _xn[128 + lane]; \
  float _nd = dones[_prn]; \
  int   _na = actions[_prn]; \
  float _nh = hid0[_prn * 64 + lane]; \
  float _ara = x0##S, _arb = 0.f, _aza = x1##S, _azb = 0.f, _ana = 0.f, _anb = 0.f; \
  _Pragma("unroll") \
  for (int _q = 0; _q < 8; ++_q) { \
    uint4 _hv = shv##S[_q]; \
    h2 _a0 = __builtin_bit_cast(h2, _hv.x); \
    h2 _a1 = __builtin_bit_cast(h2, _hv.y); \
    h2 _a2 = __builtin_bit_cast(h2, _hv.z); \
    h2 _a3 = __builtin_bit_cast(h2, _hv.w); \
    _ara = DOT2(_a0, Wr[4*_q+0], _ara); _arb = DOT2(_a1, Wr[4*_q+1], _arb); \
    _ara = DOT2(_a2, Wr[4*_q+2], _ara); _arb = DOT2(_a3, Wr[4*_q+3], _arb); \
    _aza = DOT2(_a0, Wz[4*_q+0], _aza); _azb = DOT2(_a1, Wz[4*_q+1], _azb); \
    _aza = DOT2(_a2, Wz[4*_q+2], _aza); _azb = DOT2(_a3, Wz[4*_q+3], _azb); \
    _ana = DOT2(_a0, Wn[4*_q+0], _ana); _anb = DOT2(_a1, Wn[4*_q+1], _anb); \
    _ana = DOT2(_a2, Wn[4*_q+2], _ana); _anb = DOT2(_a3, Wn[4*_q+3], _anb); \
  } \
  float _ar = _ara + _arb, _az = _aza + _azb, _an = _ana + _anb; \
  float _r = __builtin_amdgcn_rcpf(1.f + __expf(-_ar)); \
  float _z = __builtin_amdgcn_rcpf(1.f + __expf(-_az)); \
  float _pre = x2##S + _r * (_an + bhn_r); \
  float _n = 1.f - 2.f * __builtin_amdgcn_rcpf(1.f + __expf(2.f * _pre)); \
  float _hn = (1.f - _z) * _n + _z * h##S; \
  if ((lane & 1) == 0) sh2##S[lane >> 1] = pack_pair(_hn); \
  float _la = bo_r, _lb = 0.f; \
  _Pragma("unroll") \
  for (int _q = 0; _q < 8; ++_q) { \
    uint4 _hv = shv##S[_q]; \
    _la = DOT2(__builtin_bit_cast(h2, _hv.x), Wo[4*_q+0], _la); \
    _lb = DOT2(__builtin_bit_cast(h2, _hv.y), Wo[4*_q+1], _lb); \
    _la = DOT2(__builtin_bit_cast(h2, _hv.z), Wo[4*_q+2], _la); \
    _lb = DOT2(__builtin_bit_cast(h2, _hv.w), Wo[4*_q+3], _lb); \
  } \
  float _logit = _la + _lb; \
  if (lane < 18) sloge##S[lane] = __expf(_logit); \
  float4 _e0 = *(const float4*)&sloge##S[0]; \
  float4 _e1 = *(const float4*)&sloge##S[4]; \
  float4 _e2 = *(const float4*)&sloge##S[8]; \
  float4 _e3 = *(const float4*)&sloge##S[12]; \
  float4 _e4 = *(const float4*)&sloge##S[16]; \
  float _ss = (((_e0.x+_e0.y)+(_e0.z+_e0.w)) + ((_e1.x+_e1.y)+(_e1.z+_e1.w))) \
            + (((_e2.x+_e2.y)+(_e2.z+_e2.w)) + ((_e3.x+_e3.y)+(_e3.z+_e3.w))) \
            + ((_e4.x+_e4.y)+(_e4.z+_e4.w)); \
  float _lav = __builtin_bit_cast(float, __builtin_amdgcn_readlane(__builtin_bit_cast(int, _logit), act##S)); \
  if (live##S && lane == 0) atomicAdd(&out[1 + s##S * 64 + b##S], __logf(_ss) - _lav); \
  end##S = (d##S > 0.f) || (u##S == 127); \
  bool _adv = !end##S; \
  bool _rst = _adv && (_nd > 0.f); \
  h##S = _rst ? _nh : _hn; \
  if (((lane & 1) == 0) && _rst) sh2##S[lane >> 1] = pack_pair(_nh); \
  u##S  = _adv ? _un  : u##S; \
  s##S  = _adv ? s##S + 1 : s##S; \
  x0##S = _adv ? _nx0 : x0##S; x1##S = _adv ? _nx1 : x1##S; x2##S = _adv ? _nx2 : x2##S; \
  d##S  = _adv ? _nd  : d##S; \
  act##S = _adv ? _na : act##S; }

__global__ __launch_bounds__(64, 1) void rollout_kernel(
    const float* __restrict__ xi, const float* __restrict__ hid0,
    const float* __restrict__ dones, const int* __restrict__ actions,
    const float* __restrict__ Whrz, const float* __restrict__ Whn,
    const float* __restrict__ bhn, const float* __restrict__ Wout,
    const float* __restrict__ bout, float* __restrict__ out,
    unsigned int* __restrict__ ctr) {
  __shared__ __attribute__((aligned(16))) h2 sh2A[32], sh2B[32];
  __shared__ __attribute__((aligned(16))) float slogeA[20], slogeB[20];
  int lane = threadIdx.x;
  int row = (lane < 18) ? lane : 0;
  h2 Wr[32], Wz[32], Wn[32], Wo[32];   // f16-packed, shared by both slots: 128 regs
  #pragma unroll
  for (int k = 0; k < 32; ++k) {
    Wr[k] = h2{(_Float16)Whrz[(2 * k) * 128 + lane],      (_Float16)Whrz[(2 * k + 1) * 128 + lane]};
    Wz[k] = h2{(_Float16)Whrz[(2 * k) * 128 + 64 + lane], (_Float16)Whrz[(2 * k + 1) * 128 + 64 + lane]};
    Wn[k] = h2{(_Float16)Whn[(2 * k) * 64 + lane],        (_Float16)Whn[(2 * k + 1) * 64 + lane]};
    Wo[k] = h2{(_Float16)Wout[(2 * k) * 18 + row],        (_Float16)Wout[(2 * k + 1) * 18 + row]};
  }
  if (lane < 2) { slogeA[18 + lane] = 0.f; slogeB[18 + lane] = 0.f; }  // sentinels
  float bhn_r = bhn[lane];
  float bo_r = bout[row];
  __syncthreads();
  const uint4* shvA = (const uint4*)sh2A;
  const uint4* shvB = (const uint4*)sh2B;

  bool liveA, liveB;
  int uA = 0, bA = 0, sA = 0, actA = 0;
  int uB = 0, bB = 0, sB = 0, actB = 0;
  float hA = 0.f, x0A = 0.f, x1A = 0.f, x2A = 0.f, dA = 1.f;
  float hB = 0.f, x0B = 0.f, x1B = 0.f, x2B = 0.f, dB = 1.f;
  POP(A);
  POP(B);

  while (liveA || liveB) {
    bool endA, endB;
    // ---- both steps in one basic block: scheduler interleaves A/B chains ----
    STEP(A);
    STEP(B);
    // ---- pops for ended slots (uniform, rare) ----
    if (liveA && endA) POP(A);
    if (liveB && endB) POP(B);
  }
}

extern "C" void kernel_launch(void* const* d_in, const int* in_sizes, int n_in,
                              void* d_out, int out_size, void* d_ws, size_t ws_size,
                              hipStream_t stream) {
  const float* state = (const float*)d_in[0];
  const float* lm    = (const float*)d_in[1];
  const float* lv    = (const float*)d_in[2];
  const float* lmt   = (const float*)d_in[3];
  const float* lvt   = (const float*)d_in[4];
  const float* ac    = (const float*)d_in[5];
  const float* ms    = (const float*)d_in[6];
  const int*   actions = (const int*)d_in[7];
  const float* dones = (const float*)d_in[8];
  const float* Wst = (const float*)d_in[9],  *bst = (const float*)d_in[10];
  const float* Wac = (const float*)d_in[11], *bac = (const float*)d_in[12];
  const float* Wem = (const float*)d_in[13], *bem = (const float*)d_in[14];
  const float* Whd = (const float*)d_in[15], *bhd = (const float*)d_in[16];
  const float* Wi  = (const float*)d_in[17], *bi  = (const float*)d_in[18];
  const float* Whrz = (const float*)d_in[19];
  const float* Whn  = (const float*)d_in[20], *bhn = (const float*)d_in[21];
  const float* Wout = (const float*)d_in[22], *bout = (const float*)d_in[23];
  float* out = (float*)d_out;
  float* xi   = (float*)((char*)d_ws + XI_OFF);
  float* hid0 = (float*)((char*)d_ws + HID_OFF);
  unsigned int* ctr = (unsigned int*)((char*)d_ws + CTR_OFF);

  hipMemsetAsync(d_out, 0, (size_t)out_size * sizeof(float), stream);
  hipMemsetAsync(ctr, 0, sizeof(unsigned int), stream);

  hipLaunchKernelGGL(precompute_kernel, dim3(320), dim3(256), 0, stream,
                     state, ac, ms, Wst, bst, Wac, bac, Wem, bem, Whd, bhd, Wi, bi,
                     lm, lv, lmt, lvt, xi, hid0, out);
  hipLaunchKernelGGL(rollout_kernel, dim3(2048), dim3(64), 0, stream,
                     xi, hid0, dones, actions, Whrz, Whn, bhn, Wout, bout, out, ctr);
}

// Round 15
// 202.314 us; speedup vs baseline: 1.3404x; 1.3404x over previous
//
#include <hip/hip_runtime.h>

// Problem: T=128, B=64, STATE=32, LATENT=16, AC=8, MS=8, SE=64, AE=16, H=64, OUT=18
// d_out layout: [0] = kl_loss, [1 .. 8192] = recon_loss[s*64+b]  (out_size = 8193, f32)
// d_ws layout:  [0, 6291456)  xi  (T,B,192) f32   = embed@Wi + bi
//               [6291456, 8388608) hid0 (T,B,64) f32

#define XI_OFF   0
#define HID_OFF  6291456

typedef float f32x16 __attribute__((ext_vector_type(16)));
typedef _Float16 h2 __attribute__((ext_vector_type(2)));

#if __has_builtin(__builtin_amdgcn_fdot2)
#define DOT2(a, b, c) __builtin_amdgcn_fdot2((a), (b), (c), false)
#else
#define DOT2(a, b, c) ((c) + (float)(a).x * (float)(b).x + (float)(a).y * (float)(b).y)
#endif

// pack {h[lane], h[lane^1]} into h2 using DPP quad_perm [1,0,3,2] (VALU, no LDS)
__device__ __forceinline__ h2 pack_pair(float h) {
  int hb = __builtin_bit_cast(int, h);
  int hp = __builtin_amdgcn_mov_dpp(hb, 0xB1, 0xF, 0xF, true);  // lane^1
  return __builtin_bit_cast(h2, __builtin_amdgcn_cvt_pkrtz(h, __builtin_bit_cast(float, hp)));
}

// ---------------- Fused precompute (blocks 0..255) + KL (blocks 256..319) ----------------
__global__ __launch_bounds__(256, 1) void precompute_kernel(
    const float* __restrict__ state, const float* __restrict__ ac, const float* __restrict__ ms,
    const float* __restrict__ Wst, const float* __restrict__ bst,
    const float* __restrict__ Wac, const float* __restrict__ bac,
    const float* __restrict__ Wem, const float* __restrict__ bem,
    const float* __restrict__ Whd, const float* __restrict__ bhd,
    const float* __restrict__ Wi,  const float* __restrict__ bi,
    const float* __restrict__ lm, const float* __restrict__ lv,
    const float* __restrict__ lmt, const float* __restrict__ lvt,
    float* __restrict__ xi, float* __restrict__ hid0, float* __restrict__ out) {
  __shared__ float sWst[32 * 64];
  __shared__ float sWem[80 * 64];
  __shared__ float sWhd[24 * 64];
  __shared__ float sWac[8 * 16];
  __shared__ float sb[208];
  __shared__ float sin_[4][48];
  __shared__ float sse[4][80];
  __shared__ float semb[4][64];
  __shared__ float ps[4];
  int tid = threadIdx.x, lane = tid & 63, w = tid >> 6;

  if (blockIdx.x >= 256) {
    // ---- KL: 64 blocks * 256 threads * 16 iters = 262144 items ----
    float total = 0.f;
    for (int it = 0; it < 16; ++it) {
      int idx = ((int)blockIdx.x - 256) * 256 + tid + it * 16384;
      int g = idx & 31;
      int pair = idx >> 5;
      const float* M = (g < 16) ? lm : lmt;
      const float* V = (g < 16) ? lv : lvt;
      int cur = pair * 16 + (g & 15);
      float mu = M[cur], lE = V[cur];
      float m = 0.f, lS = 0.f;
      if (pair >= 64) { m = M[cur - 1024]; lS = V[cur - 1024]; }
      float d = m - mu;
      total += 0.5f * (lS - lE - 1.f + __expf(lE - lS) + d * d * __expf(-lS));
    }
    #pragma unroll
    for (int off = 32; off; off >>= 1) total += __shfl_xor(total, off);
    if (lane == 0) ps[w] = total;
    __syncthreads();
    if (tid == 0) atomicAdd(out, ps[0] + ps[1] + ps[2] + ps[3]);
    return;
  }

  // ---- precompute: 32 (t,b) pairs per block ----
  f32x16 wi0[4], wi1[4], wi2[4];
  #pragma unroll
  for (int k = 0; k < 64; ++k) {
    wi0[k >> 4][k & 15] = Wi[k * 192 + lane];
    wi1[k >> 4][k & 15] = Wi[k * 192 + 64 + lane];
    wi2[k >> 4][k & 15] = Wi[k * 192 + 128 + lane];
  }
  for (int i = tid; i < 32 * 64; i += 256) sWst[i] = Wst[i];
  for (int i = tid; i < 80 * 64; i += 256) sWem[i] = Wem[i];
  for (int i = tid; i < 24 * 64; i += 256) sWhd[i] = Whd[i];
  for (int i = tid; i < 8 * 16; i += 256) sWac[i] = Wac[i];
  if (tid < 64) sb[tid] = bst[tid];
  if (tid < 16) sb[64 + tid] = bac[tid];
  if (tid < 64) sb[80 + tid] = bem[tid];
  if (tid < 64) sb[144 + tid] = bhd[tid];
  float bi0 = bi[lane], bi1 = bi[64 + lane], bi2 = bi[128 + lane];
  __syncthreads();
  for (int cnt = 0; cnt < 8; ++cnt) {
    int pair = blockIdx.x * 32 + w * 8 + cnt;   // t*64 + b, in [0, 8192)
    if (lane < 32)      sin_[w][lane] = state[pair * 32 + lane];
    else if (lane < 40) sin_[w][lane] = ac[pair * 8 + (lane - 32)];
    else if (lane < 48) sin_[w][lane] = ms[pair * 8 + (lane - 40)];
    __syncthreads();
    float se = sb[lane];
    #pragma unroll
    for (int k = 0; k < 32; ++k) se += sin_[w][k] * sWst[k * 64 + lane];
    se = fmaxf(se, 0.f);
    float ae = 0.f;
    if (lane < 16) {
      ae = sb[64 + lane];
      #pragma unroll
      for (int k = 0; k < 8; ++k) ae += sin_[w][32 + k] * sWac[k * 16 + lane];
      ae = fmaxf(ae, 0.f);
    }
    __syncthreads();
    sse[w][lane] = se;
    if (lane < 16) sse[w][64 + lane] = ae;
    __syncthreads();
    float em = sb[80 + lane];
    #pragma unroll
    for (int k = 0; k < 80; ++k) em += sse[w][k] * sWem[k * 64 + lane];
    float hd = sb[144 + lane];
    #pragma unroll
    for (int k = 0; k < 16; ++k) hd += sse[w][64 + k] * sWhd[k * 64 + lane];
    #pragma unroll
    for (int k = 0; k < 8; ++k) hd += sin_[w][40 + k] * sWhd[(16 + k) * 64 + lane];
    hid0[pair * 64 + lane] = hd;
    semb[w][lane] = em;
    __syncthreads();
    float x0 = bi0, x1 = bi1, x2 = bi2;
    #pragma unroll
    for (int k = 0; k < 64; ++k) {
      float e = semb[w][k];
      x0 += e * wi0[k >> 4][k & 15];
      x1 += e * wi1[k >> 4][k & 15];
      x2 += e * wi2[k >> 4][k & 15];
    }
    float* xo = xi + pair * 192;
    xo[lane] = x0; xo[64 + lane] = x1; xo[128 + lane] = x2;
    __syncthreads();
  }
}

// ---------------- Rollout: phase-locked PAIRS (tA=2p, tB=2p+1), one wave each ----------
// Both rollouts step through the same absolute time u: same xi/dones/actions/hid0 loads,
// same action, same death phase (first done >= tB). Both cells computed unconditionally
// in one basic block (static ILP2); only the stores are masked. Unique output slots ->
// plain stores, no atomics. Static assignment: block = pair*64 + b (longest first).
__global__ __launch_bounds__(64, 2) void rollout_kernel(
    const float* __restrict__ xi, const float* __restrict__ hid0,
    const float* __restrict__ dones, const int* __restrict__ actions,
    const float* __restrict__ Whrz, const float* __restrict__ Whn,
    const float* __restrict__ bhn, const float* __restrict__ Wout,
    const float* __restrict__ bout, float* __restrict__ out) {
  __shared__ __attribute__((aligned(16))) h2 sh2A[32], sh2B[32];
  __shared__ __attribute__((aligned(16))) float slogeA[20], slogeB[20];
  int lane = threadIdx.x;
  int row = (lane < 18) ? lane : 0;
  h2 Wr[32], Wz[32], Wn[32], Wo[32];   // f16-packed, shared by both cells: 128 regs
  #pragma unroll
  for (int k = 0; k < 32; ++k) {
    Wr[k] = h2{(_Float16)Whrz[(2 * k) * 128 + lane],      (_Float16)Whrz[(2 * k + 1) * 128 + lane]};
    Wz[k] = h2{(_Float16)Whrz[(2 * k) * 128 + 64 + lane], (_Float16)Whrz[(2 * k + 1) * 128 + 64 + lane]};
    Wn[k] = h2{(_Float16)Whn[(2 * k) * 64 + lane],        (_Float16)Whn[(2 * k + 1) * 64 + lane]};
    Wo[k] = h2{(_Float16)Wout[(2 * k) * 18 + row],        (_Float16)Wout[(2 * k + 1) * 18 + row]};
  }
  if (lane < 2) { slogeA[18 + lane] = 0.f; slogeB[18 + lane] = 0.f; }  // sentinels
  float bhn_r = bhn[lane];
  float bo_r = bout[row];
  __syncthreads();
  const uint4* shvA = (const uint4*)sh2A;
  const uint4* shvB = (const uint4*)sh2B;

  int b = blockIdx.x & 63;
  int tA = (blockIdx.x >> 6) << 1;   // 0,2,...,126 — low blockIdx = longest, dispatched first
  int tB = tA + 1;
  int u = tA;
  int pr = u * 64 + b;
  const float* xb = xi + pr * 192;
  float x0 = xb[lane], x1 = xb[64 + lane], x2 = xb[128 + lane];
  float d = dones[pr];
  int  act = actions[pr];
  float h0u = hid0[pr * 64 + lane];
  float hA = h0u, hB = h0u;          // A: s=0 fresh start; B: defined garbage until u==tB
  bool okA = true;
  if ((lane & 1) == 0) { sh2A[lane >> 1] = pack_pair(hA); sh2B[lane >> 1] = pack_pair(hB); }

  for (;;) {
    int un = (u < 127) ? u + 1 : 127;
    int prn = un * 64 + b;
    // -------- prefetch next phase (hidden under compute) --------
    const float* xn = xi + prn * 192;
    float nx0 = xn[lane], nx1 = xn[64 + lane], nx2 = xn[128 + lane];
    float nd = dones[prn];
    int   na = actions[prn];
    float nh0 = hid0[prn * 64 + lane];
    // -------- gates for BOTH cells: 16 uniform b128 reads + 192 dot2 --------
    float arA = x0, azA = x1, anA = 0.f;
    float arB = x0, azB = x1, anB = 0.f;
    #pragma unroll
    for (int q = 0; q < 8; ++q) {
      uint4 hva = shvA[q];
      uint4 hvb = shvB[q];
      h2 a0 = __builtin_bit_cast(h2, hva.x), a1 = __builtin_bit_cast(h2, hva.y);
      h2 a2 = __builtin_bit_cast(h2, hva.z), a3 = __builtin_bit_cast(h2, hva.w);
      h2 c0 = __builtin_bit_cast(h2, hvb.x), c1 = __builtin_bit_cast(h2, hvb.y);
      h2 c2 = __builtin_bit_cast(h2, hvb.z), c3 = __builtin_bit_cast(h2, hvb.w);
      arA = DOT2(a0, Wr[4*q+0], arA); arB = DOT2(c0, Wr[4*q+0], arB);
      arA = DOT2(a1, Wr[4*q+1], arA); arB = DOT2(c1, Wr[4*q+1], arB);
      arA = DOT2(a2, Wr[4*q+2], arA); arB = DOT2(c2, Wr[4*q+2], arB);
      arA = DOT2(a3, Wr[4*q+3], arA); arB = DOT2(c3, Wr[4*q+3], arB);
      azA = DOT2(a0, Wz[4*q+0], azA); azB = DOT2(c0, Wz[4*q+0], azB);
      azA = DOT2(a1, Wz[4*q+1], azA); azB = DOT2(c1, Wz[4*q+1], azB);
      azA = DOT2(a2, Wz[4*q+2], azA); azB = DOT2(c2, Wz[4*q+2], azB);
      azA = DOT2(a3, Wz[4*q+3], azA); azB = DOT2(c3, Wz[4*q+3], azB);
      anA = DOT2(a0, Wn[4*q+0], anA); anB = DOT2(c0, Wn[4*q+0], anB);
      anA = DOT2(a1, Wn[4*q+1], anA); anB = DOT2(c1, Wn[4*q+1], anB);
      anA = DOT2(a2, Wn[4*q+2], anA); anB = DOT2(c2, Wn[4*q+2], anB);
      anA = DOT2(a3, Wn[4*q+3], anA); anB = DOT2(c3, Wn[4*q+3], anB);
    }
    // -------- GRU nonlinearity, both cells --------
    float rA = __builtin_amdgcn_rcpf(1.f + __expf(-arA));
    float rB = __builtin_amdgcn_rcpf(1.f + __expf(-arB));
    float zA = __builtin_amdgcn_rcpf(1.f + __expf(-azA));
    float zB = __builtin_amdgcn_rcpf(1.f + __expf(-azB));
    float preA = x2 + rA * (anA + bhn_r);
    float preB = x2 + rB * (anB + bhn_r);
    float nA = 1.f - 2.f * __builtin_amdgcn_rcpf(1.f + __expf(2.f * preA));
    float nB = 1.f - 2.f * __builtin_amdgcn_rcpf(1.f + __expf(2.f * preB));
    float hnA = (1.f - zA) * nA + zA * hA;
    float hnB = (1.f - zB) * nB + zB * hB;
    // -------- broadcast h_new; logits for both via register W_out rows --------
    if ((lane & 1) == 0) { sh2A[lane >> 1] = pack_pair(hnA); sh2B[lane >> 1] = pack_pair(hnB); }
    float laA = bo_r, laB = bo_r;
    #pragma unroll
    for (int q = 0; q < 8; ++q) {
      uint4 hva = shvA[q];
      uint4 hvb = shvB[q];
      laA = DOT2(__builtin_bit_cast(h2, hva.x), Wo[4*q+0], laA);
      laB = DOT2(__builtin_bit_cast(h2, hvb.x), Wo[4*q+0], laB);
      laA = DOT2(__builtin_bit_cast(h2, hva.y), Wo[4*q+1], laA);
      laB = DOT2(__builtin_bit_cast(h2, hvb.y), Wo[4*q+1], laB);
      laA = DOT2(__builtin_bit_cast(h2, hva.z), Wo[4*q+2], laA);
      laB = DOT2(__builtin_bit_cast(h2, hvb.z), Wo[4*q+2], laB);
      laA = DOT2(__builtin_bit_cast(h2, hva.w), Wo[4*q+3], laA);
      laB = DOT2(__builtin_bit_cast(h2, hvb.w), Wo[4*q+3], laB);
    }
    // -------- softmax, both cells (no max pass; logits small) --------
    if (lane < 18) { slogeA[lane] = __expf(laA); slogeB[lane] = __expf(laB); }
    float4 eA0 = *(const float4*)&slogeA[0];
    float4 eA1 = *(const float4*)&slogeA[4];
    float4 eA2 = *(const float4*)&slogeA[8];
    float4 eA3 = *(const float4*)&slogeA[12];
    float4 eA4 = *(const float4*)&slogeA[16];
    float4 eB0 = *(const float4*)&slogeB[0];
    float4 eB1 = *(const float4*)&slogeB[4];
    float4 eB2 = *(const float4*)&slogeB[8];
    float4 eB3 = *(const float4*)&slogeB[12];
    float4 eB4 = *(const float4*)&slogeB[16];
    float ssA = (((eA0.x+eA0.y)+(eA0.z+eA0.w)) + ((eA1.x+eA1.y)+(eA1.z+eA1.w)))
              + (((eA2.x+eA2.y)+(eA2.z+eA2.w)) + ((eA3.x+eA3.y)+(eA3.z+eA3.w)))
              + ((eA4.x+eA4.y)+(eA4.z+eA4.w));
    float ssB = (((eB0.x+eB0.y)+(eB0.z+eB0.w)) + ((eB1.x+eB1.y)+(eB1.z+eB1.w)))
              + (((eB2.x+eB2.y)+(eB2.z+eB2.w)) + ((eB3.x+eB3.y)+(eB3.z+eB3.w)))
              + ((eB4.x+eB4.y)+(eB4.z+eB4.w));
    float lvA = __builtin_bit_cast(float, __builtin_amdgcn_readlane(__builtin_bit_cast(int, laA), act));
    float lvB = __builtin_bit_cast(float, __builtin_amdgcn_readlane(__builtin_bit_cast(int, laB), act));
    // -------- masked plain stores (unique slots) --------
    bool aliveB = (u >= tB);
    if (lane == 0) {
      if (okA)    out[1 + (u - tA) * 64 + b] = __logf(ssA) - lvA;
      if (aliveB) out[1 + (u - tB) * 64 + b] = __logf(ssB) - lvB;
    }
    // -------- advance / break --------
    bool dpos = d > 0.f;
    if ((dpos && u >= tB) || u == 127) break;   // first done >= tB kills both (after emit)
    if (dpos) okA = false;                      // done at u == tA: kills A only
    u = un; x0 = nx0; x1 = nx1; x2 = nx2; d = nd; act = na; h0u = nh0;
    // resets for the incoming phase (uses NEW u's done flag / hid0)
    bool rst = (d > 0.f);
    bool rstB = rst || (u == tB);
    hA = rst  ? h0u : hnA;
    hB = rstB ? h0u : hnB;
    if (rst || rstB) {
      if ((lane & 1) == 0) {
        if (rst)  sh2A[lane >> 1] = pack_pair(h0u);
        if (rstB) sh2B[lane >> 1] = pack_pair(h0u);
      }
    }
  }
}

extern "C" void kernel_launch(void* const* d_in, const int* in_sizes, int n_in,
                              void* d_out, int out_size, void* d_ws, size_t ws_size,
                              hipStream_t stream) {
  const float* state = (const float*)d_in[0];
  const float* lm    = (const float*)d_in[1];
  const float* lv    = (const float*)d_in[2];
  const float* lmt   = (const float*)d_in[3];
  const float* lvt   = (const float*)d_in[4];
  const float* ac    = (const float*)d_in[5];
  const float* ms    = (const float*)d_in[6];
  const int*   actions = (const int*)d_in[7];
  const float* dones = (const float*)d_in[8];
  const float* Wst = (const float*)d_in[9],  *bst = (const float*)d_in[10];
  const float* Wac = (const float*)d_in[11], *bac = (const float*)d_in[12];
  const float* Wem = (const float*)d_in[13], *bem = (const float*)d_in[14];
  const float* Whd = (const float*)d_in[15], *bhd = (const float*)d_in[16];
  const float* Wi  = (const float*)d_in[17], *bi  = (const float*)d_in[18];
  const float* Whrz = (const float*)d_in[19];
  const float* Whn  = (const float*)d_in[20], *bhn = (const float*)d_in[21];
  const float* Wout = (const float*)d_in[22], *bout = (const float*)d_in[23];
  float* out = (float*)d_out;
  float* xi   = (float*)((char*)d_ws + XI_OFF);
  float* hid0 = (float*)((char*)d_ws + HID_OFF);

  hipMemsetAsync(d_out, 0, (size_t)out_size * sizeof(float), stream);

  hipLaunchKernelGGL(precompute_kernel, dim3(320), dim3(256), 0, stream,
                     state, ac, ms, Wst, bst, Wac, bac, Wem, bem, Whd, bhd, Wi, bi,
                     lm, lv, lmt, lvt, xi, hid0, out);
  hipLaunchKernelGGL(rollout_kernel, dim3(4096), dim3(64), 0, stream,
                     xi, hid0, dones, actions, Whrz, Whn, bhn, Wout, bout, out);
}

// Round 16
// 177.508 us; speedup vs baseline: 1.5277x; 1.1397x over previous
//
#include <hip/hip_runtime.h>

// Problem: T=128, B=64, STATE=32, LATENT=16, AC=8, MS=8, SE=64, AE=16, H=64, OUT=18
// d_out layout: [0] = kl_loss, [1 .. 8192] = recon_loss[s*64+b]  (out_size = 8193, f32)
// d_ws layout:  [0, 3145728)        xi16  (T,B,192) f16 = embed@Wi + bi
//               [3145728, 4194304)  hid16 (T,B,64)  f16
//               [4194304, +32)      8 work-steal counters (one per XCD queue)

#define XI_OFF   0
#define HID_OFF  3145728
#define CTR_OFF  4194304

typedef float f32x16 __attribute__((ext_vector_type(16)));
typedef _Float16 h2 __attribute__((ext_vector_type(2)));

#if __has_builtin(__builtin_amdgcn_fdot2)
#define DOT2(a, b, c) __builtin_amdgcn_fdot2((a), (b), (c), false)
#else
#define DOT2(a, b, c) ((c) + (float)(a).x * (float)(b).x + (float)(a).y * (float)(b).y)
#endif

// pack {h[lane], h[lane^1]} into h2 using DPP quad_perm [1,0,3,2] (VALU, no LDS)
__device__ __forceinline__ h2 pack_pair(float h) {
  int hb = __builtin_bit_cast(int, h);
  int hp = __builtin_amdgcn_mov_dpp(hb, 0xB1, 0xF, 0xF, true);  // lane^1
  return __builtin_bit_cast(h2, __builtin_amdgcn_cvt_pkrtz(h, __builtin_bit_cast(float, hp)));
}

// ---------------- Fused precompute (blocks 0..255) + KL (blocks 256..319) ----------------
__global__ __launch_bounds__(256, 1) void precompute_kernel(
    const float* __restrict__ state, const float* __restrict__ ac, const float* __restrict__ ms,
    const float* __restrict__ Wst, const float* __restrict__ bst,
    const float* __restrict__ Wac, const float* __restrict__ bac,
    const float* __restrict__ Wem, const float* __restrict__ bem,
    const float* __restrict__ Whd, const float* __restrict__ bhd,
    const float* __restrict__ Wi,  const float* __restrict__ bi,
    const float* __restrict__ lm, const float* __restrict__ lv,
    const float* __restrict__ lmt, const float* __restrict__ lvt,
    _Float16* __restrict__ xi16, _Float16* __restrict__ hid16, float* __restrict__ out) {
  __shared__ float sWst[32 * 64];
  __shared__ float sWem[80 * 64];
  __shared__ float sWhd[24 * 64];
  __shared__ float sWac[8 * 16];
  __shared__ float sb[208];
  __shared__ float sin_[4][48];
  __shared__ float sse[4][80];
  __shared__ float semb[4][64];
  __shared__ float ps[4];
  int tid = threadIdx.x, lane = tid & 63, w = tid >> 6;

  if (blockIdx.x >= 256) {
    // ---- KL: 64 blocks * 256 threads * 16 iters = 262144 items ----
    float total = 0.f;
    for (int it = 0; it < 16; ++it) {
      int idx = ((int)blockIdx.x - 256) * 256 + tid + it * 16384;
      int g = idx & 31;
      int pair = idx >> 5;
      const float* M = (g < 16) ? lm : lmt;
      const float* V = (g < 16) ? lv : lvt;
      int cur = pair * 16 + (g & 15);
      float mu = M[cur], lE = V[cur];
      float m = 0.f, lS = 0.f;
      if (pair >= 64) { m = M[cur - 1024]; lS = V[cur - 1024]; }
      float d = m - mu;
      total += 0.5f * (lS - lE - 1.f + __expf(lE - lS) + d * d * __expf(-lS));
    }
    #pragma unroll
    for (int off = 32; off; off >>= 1) total += __shfl_xor(total, off);
    if (lane == 0) ps[w] = total;
    __syncthreads();
    if (tid == 0) atomicAdd(out, ps[0] + ps[1] + ps[2] + ps[3]);
    return;
  }

  // ---- precompute: 32 (t,b) pairs per block ----
  f32x16 wi0[4], wi1[4], wi2[4];
  #pragma unroll
  for (int k = 0; k < 64; ++k) {
    wi0[k >> 4][k & 15] = Wi[k * 192 + lane];
    wi1[k >> 4][k & 15] = Wi[k * 192 + 64 + lane];
    wi2[k >> 4][k & 15] = Wi[k * 192 + 128 + lane];
  }
  for (int i = tid; i < 32 * 64; i += 256) sWst[i] = Wst[i];
  for (int i = tid; i < 80 * 64; i += 256) sWem[i] = Wem[i];
  for (int i = tid; i < 24 * 64; i += 256) sWhd[i] = Whd[i];
  for (int i = tid; i < 8 * 16; i += 256) sWac[i] = Wac[i];
  if (tid < 64) sb[tid] = bst[tid];
  if (tid < 16) sb[64 + tid] = bac[tid];
  if (tid < 64) sb[80 + tid] = bem[tid];
  if (tid < 64) sb[144 + tid] = bhd[tid];
  float bi0 = bi[lane], bi1 = bi[64 + lane], bi2 = bi[128 + lane];
  __syncthreads();
  for (int cnt = 0; cnt < 8; ++cnt) {
    int pair = blockIdx.x * 32 + w * 8 + cnt;   // t*64 + b, in [0, 8192)
    if (lane < 32)      sin_[w][lane] = state[pair * 32 + lane];
    else if (lane < 40) sin_[w][lane] = ac[pair * 8 + (lane - 32)];
    else if (lane < 48) sin_[w][lane] = ms[pair * 8 + (lane - 40)];
    __syncthreads();
    float se = sb[lane];
    #pragma unroll
    for (int k = 0; k < 32; ++k) se += sin_[w][k] * sWst[k * 64 + lane];
    se = fmaxf(se, 0.f);
    float ae = 0.f;
    if (lane < 16) {
      ae = sb[64 + lane];
      #pragma unroll
      for (int k = 0; k < 8; ++k) ae += sin_[w][32 + k] * sWac[k * 16 + lane];
      ae = fmaxf(ae, 0.f);
    }
    __syncthreads();
    sse[w][lane] = se;
    if (lane < 16) sse[w][64 + lane] = ae;
    __syncthreads();
    float em = sb[80 + lane];
    #pragma unroll
    for (int k = 0; k < 80; ++k) em += sse[w][k] * sWem[k * 64 + lane];
    float hd = sb[144 + lane];
    #pragma unroll
    for (int k = 0; k < 16; ++k) hd += sse[w][64 + k] * sWhd[k * 64 + lane];
    #pragma unroll
    for (int k = 0; k < 8; ++k) hd += sin_[w][40 + k] * sWhd[(16 + k) * 64 + lane];
    hid16[pair * 64 + lane] = (_Float16)hd;
    semb[w][lane] = em;
    __syncthreads();
    float x0 = bi0, x1 = bi1, x2 = bi2;
    #pragma unroll
    for (int k = 0; k < 64; ++k) {
      float e = semb[w][k];
      x0 += e * wi0[k >> 4][k & 15];
      x1 += e * wi1[k >> 4][k & 15];
      x2 += e * wi2[k >> 4][k & 15];
    }
    _Float16* xo = xi16 + pair * 192;
    xo[lane] = (_Float16)x0; xo[64 + lane] = (_Float16)x1; xo[128 + lane] = (_Float16)x2;
    __syncthreads();
  }
}

// ---------------- Rollout: one wave per (t,b) sequence, XCD-local queues ----------------
// Round-8 body (proven 152us, VGPR~130, no spill) + two locality changes:
//  (1) 8 queues keyed by blockIdx&7 (~XCD id); queue q owns b with b&7==q ->
//      per-XCD working set ~0.5MB << 4MB L2 (was 8MB thrash at 900cy/miss).
//  (2) xi/hid0 in f16: half the traffic.
__global__ __launch_bounds__(64, 2) void rollout_kernel(
    const _Float16* __restrict__ xi16, const _Float16* __restrict__ hid16,
    const float* __restrict__ dones, const int* __restrict__ actions,
    const float* __restrict__ Whrz, const float* __restrict__ Whn,
    const float* __restrict__ bhn, const float* __restrict__ Wout,
    const float* __restrict__ bout, float* __restrict__ out,
    unsigned int* __restrict__ ctrs) {
  __shared__ __attribute__((aligned(16))) h2 sh2[32];        // packed h broadcast
  __shared__ __attribute__((aligned(16))) float sloge[20];   // exp(logit); [18],[19]=0
  int lane = threadIdx.x;
  int row = (lane < 18) ? lane : 0;
  h2 Wr[32], Wz[32], Wn[32], Wo[32];   // f16-packed: 128 regs
  #pragma unroll
  for (int k = 0; k < 32; ++k) {
    Wr[k] = h2{(_Float16)Whrz[(2 * k) * 128 + lane],      (_Float16)Whrz[(2 * k + 1) * 128 + lane]};
    Wz[k] = h2{(_Float16)Whrz[(2 * k) * 128 + 64 + lane], (_Float16)Whrz[(2 * k + 1) * 128 + 64 + lane]};
    Wn[k] = h2{(_Float16)Whn[(2 * k) * 64 + lane],        (_Float16)Whn[(2 * k + 1) * 64 + lane]};
    Wo[k] = h2{(_Float16)Wout[(2 * k) * 18 + row],        (_Float16)Wout[(2 * k + 1) * 18 + row]};
  }
  if (lane < 2) sloge[18 + lane] = 0.f;          // sentinels: exp contribution 0
  float bhn_r = bhn[lane];
  float bo_r = bout[row];
  __syncthreads();
  const uint4* shv = (const uint4*)sh2;
  int q = blockIdx.x & 7;                        // ~XCD id under round-robin dispatch
  while (true) {
    int i = 0;
    if (lane == 0) i = (int)atomicAdd(&ctrs[q], 1u);
    i = __shfl(i, 0);
    if (i >= 1024) break;
    int t = i >> 3, b = ((i & 7) << 3) | q;      // queue q owns b&7==q; t-ascending (LPT)
    int u = t;
    int pr = (t << 6) | b;
    float h = (float)hid16[pr * 64 + lane];      // covers the s=0 reset case too
    const _Float16* xb = xi16 + pr * 192;
    float x0 = (float)xb[lane], x1 = (float)xb[64 + lane], x2 = (float)xb[128 + lane];
    float d = dones[pr];
    int  act = actions[pr];
    if ((lane & 1) == 0) sh2[lane >> 1] = pack_pair(h);
    for (int s = 0;; ++s) {
      int un = (u < 127) ? u + 1 : 127;
      int prn = (un << 6) | b;
      // -------- prefetch next step (hidden under compute; L2-resident slice) --------
      const _Float16* xn = xi16 + prn * 192;
      float nx0 = (float)xn[lane], nx1 = (float)xn[64 + lane], nx2 = (float)xn[128 + lane];
      float nd = dones[prn];
      int   na = actions[prn];
      float nh = (float)hid16[prn * 64 + lane];
      // -------- GRU gates: 8 uniform b128 reads + 96 dot2 --------
      float ara = x0, arb = 0.f, aza = x1, azb = 0.f, ana = 0.f, anb = 0.f;
      #pragma unroll
      for (int qq = 0; qq < 8; ++qq) {
        uint4 hv = shv[qq];                       // broadcast (same addr all lanes)
        h2 a0 = __builtin_bit_cast(h2, hv.x);
        h2 a1 = __builtin_bit_cast(h2, hv.y);
        h2 a2 = __builtin_bit_cast(h2, hv.z);
        h2 a3 = __builtin_bit_cast(h2, hv.w);
        ara = DOT2(a0, Wr[4 * qq + 0], ara); arb = DOT2(a1, Wr[4 * qq + 1], arb);
        ara = DOT2(a2, Wr[4 * qq + 2], ara); arb = DOT2(a3, Wr[4 * qq + 3], arb);
        aza = DOT2(a0, Wz[4 * qq + 0], aza); azb = DOT2(a1, Wz[4 * qq + 1], azb);
        aza = DOT2(a2, Wz[4 * qq + 2], aza); azb = DOT2(a3, Wz[4 * qq + 3], azb);
        ana = DOT2(a0, Wn[4 * qq + 0], ana); anb = DOT2(a1, Wn[4 * qq + 1], anb);
        ana = DOT2(a2, Wn[4 * qq + 2], ana); anb = DOT2(a3, Wn[4 * qq + 3], anb);
      }
      float ar = ara + arb, az = aza + azb, an = ana + anb;
      float r = __builtin_amdgcn_rcpf(1.f + __expf(-ar));
      float z = __builtin_amdgcn_rcpf(1.f + __expf(-az));
      float pre = x2 + r * (an + bhn_r);
      float n = 1.f - 2.f * __builtin_amdgcn_rcpf(1.f + __expf(2.f * pre));  // tanh
      float hn = (1.f - z) * n + z * h;
      // -------- broadcast h_new; logits via register W_out rows --------
      if ((lane & 1) == 0) sh2[lane >> 1] = pack_pair(hn);
      float la_a = bo_r, la_b = 0.f;
      #pragma unroll
      for (int qq = 0; qq < 8; ++qq) {
        uint4 hv = shv[qq];
        la_a = DOT2(__builtin_bit_cast(h2, hv.x), Wo[4 * qq + 0], la_a);
        la_b = DOT2(__builtin_bit_cast(h2, hv.y), Wo[4 * qq + 1], la_b);
        la_a = DOT2(__builtin_bit_cast(h2, hv.z), Wo[4 * qq + 2], la_a);
        la_b = DOT2(__builtin_bit_cast(h2, hv.w), Wo[4 * qq + 3], la_b);
      }
      float logit = la_a + la_b;
      // -------- softmax without max pass (|logit| small by construction) --------
      if (lane < 18) sloge[lane] = __expf(logit);
      float4 e0 = *(const float4*)&sloge[0];
      float4 e1 = *(const float4*)&sloge[4];
      float4 e2 = *(const float4*)&sloge[8];
      float4 e3 = *(const float4*)&sloge[12];
      float4 e4 = *(const float4*)&sloge[16];    // [18],[19] are 0
      float ssum = (((e0.x + e0.y) + (e0.z + e0.w)) + ((e1.x + e1.y) + (e1.z + e1.w)))
                 + (((e2.x + e2.y) + (e2.z + e2.w)) + ((e3.x + e3.y) + (e3.z + e3.w)))
                 + ((e4.x + e4.y) + (e4.z + e4.w));
      float la = __builtin_bit_cast(float, __builtin_amdgcn_readlane(__builtin_bit_cast(int, logit), act));
      float lse = __logf(ssum);
      if (lane == 0) atomicAdd(&out[1 + s * 64 + b], lse - la);
      if (d > 0.f || u == 127) break;            // mask is 0 for all later steps
      // -------- advance --------
      u = un; x0 = nx0; x1 = nx1; x2 = nx2; d = nd; act = na;
      if (nd > 0.f) {
        h = nh;                                  // episode reset at next step start
        if ((lane & 1) == 0) sh2[lane >> 1] = pack_pair(h);
      } else {
        h = hn;                                  // sh2 already holds hn
      }
    }
  }
}

extern "C" void kernel_launch(void* const* d_in, const int* in_sizes, int n_in,
                              void* d_out, int out_size, void* d_ws, size_t ws_size,
                              hipStream_t stream) {
  const float* state = (const float*)d_in[0];
  const float* lm    = (const float*)d_in[1];
  const float* lv    = (const float*)d_in[2];
  const float* lmt   = (const float*)d_in[3];
  const float* lvt   = (const float*)d_in[4];
  const float* ac    = (const float*)d_in[5];
  const float* ms    = (const float*)d_in[6];
  const int*   actions = (const int*)d_in[7];
  const float* dones = (const float*)d_in[8];
  const float* Wst = (const float*)d_in[9],  *bst = (const float*)d_in[10];
  const float* Wac = (const float*)d_in[11], *bac = (const float*)d_in[12];
  const float* Wem = (const float*)d_in[13], *bem = (const float*)d_in[14];
  const float* Whd = (const float*)d_in[15], *bhd = (const float*)d_in[16];
  const float* Wi  = (const float*)d_in[17], *bi  = (const float*)d_in[18];
  const float* Whrz = (const float*)d_in[19];
  const float* Whn  = (const float*)d_in[20], *bhn = (const float*)d_in[21];
  const float* Wout = (const float*)d_in[22], *bout = (const float*)d_in[23];
  float* out = (float*)d_out;
  _Float16* xi16  = (_Float16*)((char*)d_ws + XI_OFF);
  _Float16* hid16 = (_Float16*)((char*)d_ws + HID_OFF);
  unsigned int* ctrs = (unsigned int*)((char*)d_ws + CTR_OFF);

  hipMemsetAsync(d_out, 0, (size_t)out_size * sizeof(float), stream);
  hipMemsetAsync(ctrs, 0, 8 * sizeof(unsigned int), stream);

  hipLaunchKernelGGL(precompute_kernel, dim3(320), dim3(256), 0, stream,
                     state, ac, ms, Wst, bst, Wac, bac, Wem, bem, Whd, bhd, Wi, bi,
                     lm, lv, lmt, lvt, xi16, hid16, out);
  hipLaunchKernelGGL(rollout_kernel, dim3(2048), dim3(64), 0, stream,
                     xi16, hid16, dones, actions, Whrz, Whn, bhn, Wout, bout, out, ctrs);
}